// Round 3
// baseline (1312.678 us; speedup 1.0000x reference)
//
#include <hip/hip_runtime.h>
#include <hip/hip_bf16.h>
#include <math.h>

// Model dims
#define NB 2
#define LSEQ 1024
#define DM 512
#define FFD 2048
#define NHEAD 8
#define DKH 64
#define NLAYER 4
#define VOCAB 8000
#define VPAD 8192           // vocab padded to /256
#define NCHUNK 16           // L / 64
#define NROWS (NB * LSEQ)   // 2048
#define QS 1536             // fused QKV row stride

#define OP_NONE 0
#define OP_ELU1 1
#define OP_GELU 2
#define OP_QKV  3   // elu+1 for col<1024 (Q,K), none for V

typedef __attribute__((ext_vector_type(8))) short short8;
typedef __attribute__((ext_vector_type(4))) float f32x4;
typedef __hip_bfloat16 bf16;

// ---------------------------------------------------------------------------
// 32x32 transpose-cast tile body: src (K,N) fp32 -> dst (Npad,K) bf16.
// ---------------------------------------------------------------------------
__device__ __forceinline__ void cast_tile(
    const float* __restrict__ s, bf16* __restrict__ d, int K, int N,
    int n0, int k0, int tx, int ty)
{
    __shared__ float tile[32][33];
    #pragma unroll
    for (int i = 0; i < 4; ++i) {
        const int k = k0 + ty + 8 * i;
        const int n = n0 + tx;
        tile[ty + 8 * i][tx] = (n < N) ? s[(size_t)k * N + n] : 0.f;
    }
    __syncthreads();
    #pragma unroll
    for (int i = 0; i < 4; ++i) {
        const int n = n0 + ty + 8 * i;
        d[(size_t)n * K + k0 + tx] = __float2bfloat16(tile[tx][ty + 8 * i]);
    }
}

__global__ __launch_bounds__(256) void cast_t(
    const float* __restrict__ src, bf16* __restrict__ dst,
    int K, int N, size_t sStride, size_t dStride)
{
    const int z = blockIdx.z;
    cast_tile(src + (size_t)z * sStride, dst + (size_t)z * dStride, K, N,
              blockIdx.x * 32, blockIdx.y * 32,
              threadIdx.x & 31, threadIdx.x >> 5);
}

// Batched cast for Wq/Wk/Wv/Wo (all 512x512, 4 layers): z = layer*4 + which
__global__ __launch_bounds__(256) void cast_qkvo(
    const float* __restrict__ Wq, const float* __restrict__ Wk,
    const float* __restrict__ Wv, const float* __restrict__ Wo,
    bf16* __restrict__ QKVt, bf16* __restrict__ Wot)
{
    const int z = blockIdx.z, layer = z >> 2, which = z & 3;
    const float* src = (which == 0 ? Wq : which == 1 ? Wk : which == 2 ? Wv : Wo)
                       + (size_t)layer * 262144;
    bf16* dst = (which < 3) ? (QKVt + (size_t)layer * 786432 + (size_t)which * 262144)
                            : (Wot + (size_t)layer * 262144);
    cast_tile(src, dst, 512, 512, blockIdx.x * 32, blockIdx.y * 32,
              threadIdx.x & 31, threadIdx.x >> 5);
}

// W_ei (z=0) and W_pi (z=1), both 512x512
__global__ __launch_bounds__(256) void cast_small(
    const float* __restrict__ Wei, const float* __restrict__ Wpi,
    bf16* __restrict__ Weit, bf16* __restrict__ Wpit)
{
    const int z = blockIdx.z;
    cast_tile(z == 0 ? Wei : Wpi, z == 0 ? Weit : Wpit, 512, 512,
              blockIdx.x * 32, blockIdx.y * 32,
              threadIdx.x & 31, threadIdx.x >> 5);
}

// Elementwise fp32 -> bf16 (layout preserved)
__global__ __launch_bounds__(256) void cast_e(
    const float* __restrict__ src, bf16* __restrict__ dst, int n4)
{
    const int i = blockIdx.x * 256 + threadIdx.x;
    if (i < n4) {
        const float4 v = *(const float4*)(src + (size_t)i * 4);
        dst[(size_t)i * 4 + 0] = __float2bfloat16(v.x);
        dst[(size_t)i * 4 + 1] = __float2bfloat16(v.y);
        dst[(size_t)i * 4 + 2] = __float2bfloat16(v.z);
        dst[(size_t)i * 4 + 3] = __float2bfloat16(v.w);
    }
}

// Build fused QKV bias (NL,1536)
__global__ __launch_bounds__(256) void qkv_bias_k(
    const float* __restrict__ bq, const float* __restrict__ bk,
    const float* __restrict__ bv, float* __restrict__ out)
{
    const int z = blockIdx.x;
    for (int j = threadIdx.x; j < QS; j += 256) {
        float v;
        if (j < 512)       v = bq[z * DM + j];
        else if (j < 1024) v = bk[z * DM + j - 512];
        else               v = bv[z * DM + j - 1024];
        out[z * QS + j] = v;
    }
}

// ---------------------------------------------------------------------------
// bf16 MFMA GEMM (m97 structure): C = op(A @ B + bias) [+ res]
// ---------------------------------------------------------------------------
template<int BM, int BN>
__global__ __launch_bounds__(256) void gemm16(
    const bf16* __restrict__ A, const bf16* __restrict__ Bt,
    const float* __restrict__ bias, const float* __restrict__ res,
    float* __restrict__ outF, bf16* __restrict__ outH,
    int M, int K, int Nout, int op)
{
    constexpr int WM = BM / 2, WN = BN / 2, MI = WM / 16, NI = WN / 16;
    __shared__ bf16 As[BM * 32];
    __shared__ bf16 Bs[BN * 32];
    const int tid = threadIdx.x;
    const int lane = tid & 63;
    const int wave = tid >> 6;
    const int wm = (wave >> 1) * WM, wn = (wave & 1) * WN;
    const int bm = blockIdx.y * BM, bn = blockIdx.x * BN;
    const int l16 = lane & 15, quad = lane >> 4;

    const int rA = tid >> 2;
    const int c8 = (tid & 3) << 3;

    f32x4 acc[MI][NI];
    #pragma unroll
    for (int i = 0; i < MI; ++i)
        #pragma unroll
        for (int j = 0; j < NI; ++j) acc[i][j] = (f32x4){0.f, 0.f, 0.f, 0.f};

    const bf16* gA = A  + (size_t)(bm + rA) * K + c8;
    const bf16* gB = Bt + (size_t)(bn + rA) * K + c8;
    const int ldsWaveOff = wave * 1024;

    for (int k0 = 0; k0 < K; k0 += 32) {
        __syncthreads();
        #pragma unroll
        for (int i = 0; i < BM / 64; ++i)
            __builtin_amdgcn_global_load_lds(
                (const __attribute__((address_space(1))) void*)(gA + (size_t)i * 64 * K + k0),
                (__attribute__((address_space(3))) void*)((char*)As + i * 4096 + ldsWaveOff),
                16, 0, 0);
        #pragma unroll
        for (int i = 0; i < BN / 64; ++i)
            __builtin_amdgcn_global_load_lds(
                (const __attribute__((address_space(1))) void*)(gB + (size_t)i * 64 * K + k0),
                (__attribute__((address_space(3))) void*)((char*)Bs + i * 4096 + ldsWaveOff),
                16, 0, 0);
        __syncthreads();
        short8 a[MI], b[NI];
        #pragma unroll
        for (int i = 0; i < MI; ++i)
            a[i] = *(const short8*)(As + (size_t)(wm + i * 16 + l16) * 32 + quad * 8);
        #pragma unroll
        for (int j = 0; j < NI; ++j)
            b[j] = *(const short8*)(Bs + (size_t)(wn + j * 16 + l16) * 32 + quad * 8);
        #pragma unroll
        for (int i = 0; i < MI; ++i)
            #pragma unroll
            for (int j = 0; j < NI; ++j)
                acc[i][j] = __builtin_amdgcn_mfma_f32_16x16x32_bf16(
                    a[i], b[j], acc[i][j], 0, 0, 0);
    }

    #pragma unroll
    for (int j = 0; j < NI; ++j) {
        const int col = bn + wn + j * 16 + l16;
        const bool cok = (col < Nout);
        const float bz = cok ? bias[col] : 0.f;
        #pragma unroll
        for (int i = 0; i < MI; ++i) {
            #pragma unroll
            for (int r = 0; r < 4; ++r) {
                const int row = bm + wm + i * 16 + quad * 4 + r;
                float v = acc[i][j][r] + bz;
                if (op == OP_ELU1)      v = (v > 0.f) ? v + 1.f : expf(v);
                else if (op == OP_GELU) v = 0.5f * v * (1.f + erff(v * 0.70710678118654752f));
                else if (op == OP_QKV && col < 1024) v = (v > 0.f) ? v + 1.f : expf(v);
                if (cok) {
                    if (res)  v += res[(size_t)row * Nout + col];
                    if (outF) outF[(size_t)row * Nout + col] = v;
                    if (outH) outH[(size_t)row * Nout + col] = __float2bfloat16(v);
                }
            }
        }
    }
}

// ---------------------------------------------------------------------------
// Embedding combine. gI = x_img @ W_ei + b_ei (precomputed fp32).
// ---------------------------------------------------------------------------
__global__ __launch_bounds__(256) void embed_k(
    const float* __restrict__ gI, const int* __restrict__ xt,
    const float* __restrict__ emb,
    const float* __restrict__ mi, const float* __restrict__ mt,
    const float* __restrict__ pr, const float* __restrict__ pc,
    const float* __restrict__ pt, float* __restrict__ X, bf16* __restrict__ Xh)
{
    const int row = blockIdx.x;
    const float prv = pr[row], pcv = pc[row], ptv = pt[row];
    const float miv = mi[row], mtv = mt[row];
    const int tok = xt[row];
    const float LOG1E4 = 9.2103403719761836f;
    const float LI127 = LOG1E4 / 127.f;
    const float LI255 = LOG1E4 / 255.f;

    for (int d = threadIdx.x; d < DM; d += 256) {
        float ip;
        if (d < 128)       ip = sinf(prv * expf(-(float)d * LI127));
        else if (d < 256)  ip = cosf(prv * expf(-(float)(d - 128) * LI127));
        else if (d < 384)  ip = sinf(pcv * expf(-(float)(d - 256) * LI127));
        else               ip = cosf(pcv * expf(-(float)(d - 384) * LI127));
        float tp;
        if (d < 256) tp = sinf(ptv * expf(-(float)d * LI255));
        else         tp = cosf(ptv * expf(-(float)(d - 256) * LI255));
        const float v = miv * (gI[(size_t)row * DM + d] + ip)
                      + mtv * (emb[(size_t)tok * DM + d] + tp);
        X[(size_t)row * DM + d] = v;
        Xh[(size_t)row * DM + d] = __float2bfloat16(v);
    }
}

// ---------------------------------------------------------------------------
// LayerNorm over last dim (512), fp32 + bf16 outputs.
// ---------------------------------------------------------------------------
__global__ __launch_bounds__(256) void ln_k(
    const float* __restrict__ in, const float* __restrict__ g,
    const float* __restrict__ b, float* __restrict__ out, bf16* __restrict__ outh)
{
    const int row = blockIdx.x;
    const int tid = threadIdx.x;
    const float* x = in + (size_t)row * DM;
    const float x0 = x[tid], x1 = x[tid + 256];
    __shared__ float red[256];

    red[tid] = x0 + x1;
    __syncthreads();
    for (int off = 128; off > 0; off >>= 1) {
        if (tid < off) red[tid] += red[tid + off];
        __syncthreads();
    }
    const float mean = red[0] / (float)DM;
    __syncthreads();
    const float d0 = x0 - mean, d1 = x1 - mean;
    red[tid] = d0 * d0 + d1 * d1;
    __syncthreads();
    for (int off = 128; off > 0; off >>= 1) {
        if (tid < off) red[tid] += red[tid + off];
        __syncthreads();
    }
    const float var = red[0] / (float)DM;
    const float rstd = rsqrtf(var + 1e-5f);
    const float y0 = d0 * rstd * g[tid] + b[tid];
    const float y1 = d1 * rstd * g[tid + 256] + b[tid + 256];
    out[(size_t)row * DM + tid]        = y0;
    out[(size_t)row * DM + tid + 256]  = y1;
    outh[(size_t)row * DM + tid]       = __float2bfloat16(y0);
    outh[(size_t)row * DM + tid + 256] = __float2bfloat16(y1);
}

// ---------------------------------------------------------------------------
// Chunked-parallel linear attention.
// Kernel 1: S_c = K_c^T @ V_c (64x64) and ksum_c. Grid (16,8,2).
// ---------------------------------------------------------------------------
__global__ __launch_bounds__(256) void attn_kv(
    const float* __restrict__ Kp, const float* __restrict__ Vp,
    float* __restrict__ S, float* __restrict__ ks)
{
    const int c = blockIdx.x, h = blockIdx.y, n = blockIdx.z;
    const int tid = threadIdx.x;
    __shared__ float sK[64][64], sV[64][64], part[4][64];

    const int lr = tid >> 4;           // 0..15
    const int c4 = (tid & 15) * 4;
    #pragma unroll
    for (int it = 0; it < 4; ++it) {
        const int row = it * 16 + lr;
        const size_t gb = ((size_t)(n * LSEQ + c * 64 + row)) * QS + h * DKH + c4;
        *(float4*)&sK[row][c4] = *(const float4*)(Kp + gb);
        *(float4*)&sV[row][c4] = *(const float4*)(Vp + gb);
    }
    __syncthreads();

    const int e = tid & 63, dq = tid >> 6;
    float s[16] = {};
    for (int l = 0; l < 64; ++l) {
        const float vv = sV[l][e];
        const float4 k0 = *(const float4*)&sK[l][dq * 16 + 0];
        const float4 k1 = *(const float4*)&sK[l][dq * 16 + 4];
        const float4 k2 = *(const float4*)&sK[l][dq * 16 + 8];
        const float4 k3 = *(const float4*)&sK[l][dq * 16 + 12];
        s[0]  = fmaf(k0.x, vv, s[0]);  s[1]  = fmaf(k0.y, vv, s[1]);
        s[2]  = fmaf(k0.z, vv, s[2]);  s[3]  = fmaf(k0.w, vv, s[3]);
        s[4]  = fmaf(k1.x, vv, s[4]);  s[5]  = fmaf(k1.y, vv, s[5]);
        s[6]  = fmaf(k1.z, vv, s[6]);  s[7]  = fmaf(k1.w, vv, s[7]);
        s[8]  = fmaf(k2.x, vv, s[8]);  s[9]  = fmaf(k2.y, vv, s[9]);
        s[10] = fmaf(k2.z, vv, s[10]); s[11] = fmaf(k2.w, vv, s[11]);
        s[12] = fmaf(k3.x, vv, s[12]); s[13] = fmaf(k3.y, vv, s[13]);
        s[14] = fmaf(k3.z, vv, s[14]); s[15] = fmaf(k3.w, vv, s[15]);
    }
    const size_t sb = (((size_t)(n * NHEAD + h)) * NCHUNK + c) * 4096;
    #pragma unroll
    for (int i = 0; i < 16; ++i) S[sb + (size_t)(dq * 16 + i) * 64 + e] = s[i];

    float kp = 0.f;
    #pragma unroll
    for (int i = 0; i < 16; ++i) kp += sK[dq * 16 + i][e];
    part[dq][e] = kp;
    __syncthreads();
    if (tid < 64)
        ks[(((size_t)(n * NHEAD + h)) * NCHUNK + c) * 64 + tid] =
            part[0][tid] + part[1][tid] + part[2][tid] + part[3][tid];
}

// Kernel 2: exclusive prefix over chunks, coalesced, in-place. Grid = N*H.
__global__ __launch_bounds__(256) void attn_prefix(
    float* __restrict__ S, float* __restrict__ ks)
{
    const int nh = blockIdx.x;
    const int tid = threadIdx.x;
    float run[16];
    #pragma unroll
    for (int i = 0; i < 16; ++i) run[i] = 0.f;
    float krun = 0.f;
    for (int c = 0; c < NCHUNK; ++c) {
        const size_t sb = (((size_t)nh) * NCHUNK + c) * 4096;
        #pragma unroll
        for (int i = 0; i < 16; ++i) {
            const size_t idx = sb + i * 256 + tid;
            const float t = S[idx];
            S[idx] = run[i];
            run[i] += t;
        }
        if (tid < 64) {
            const size_t kb = (((size_t)nh) * NCHUNK + c) * 64;
            const float t = ks[kb + tid];
            ks[kb + tid] = krun;
            krun += t;
        }
    }
}

// Kernel 3: O = Q@S_pre + tril(Q@K^T)@V, Z = Q.kpre + rowsum(tril(QK^T)).
// Grid (16,8,2). Register-blocked 4x4 per thread.
__global__ __launch_bounds__(256) void attn_out(
    const float* __restrict__ QKV, const float* __restrict__ S,
    const float* __restrict__ ks, bf16* __restrict__ O)
{
    const int c = blockIdx.x, h = blockIdx.y, n = blockIdx.z;
    const int tid = threadIdx.x;
    __shared__ float sQt[64][64];   // [d][l]
    __shared__ float sKt[64][64];   // [d][m]
    __shared__ float sV [64][64];   // [m][e]
    __shared__ float sS [64][64];   // [d][e]
    __shared__ float sPt[64][65];   // [m][l] (+1 pad: column reads 2-way only)
    __shared__ float skp[64];

    const int lr = tid >> 4;
    const int c4 = (tid & 15) * 4;
    const size_t sb = (((size_t)(n * NHEAD + h)) * NCHUNK + c) * 4096;
    #pragma unroll
    for (int it = 0; it < 4; ++it) {
        const int row = it * 16 + lr;
        const size_t gb = ((size_t)(n * LSEQ + c * 64 + row)) * QS + h * DKH + c4;
        const float4 q4 = *(const float4*)(QKV + gb);
        const float4 k4 = *(const float4*)(QKV + gb + 512);
        const float4 v4 = *(const float4*)(QKV + gb + 1024);
        sQt[c4 + 0][row] = q4.x; sQt[c4 + 1][row] = q4.y;
        sQt[c4 + 2][row] = q4.z; sQt[c4 + 3][row] = q4.w;
        sKt[c4 + 0][row] = k4.x; sKt[c4 + 1][row] = k4.y;
        sKt[c4 + 2][row] = k4.z; sKt[c4 + 3][row] = k4.w;
        *(float4*)&sV[row][c4] = v4;
        *(float4*)&sS[row][c4] = *(const float4*)(S + sb + (size_t)row * 64 + c4);
    }
    if (tid < 64) skp[tid] = ks[(((size_t)(n * NHEAD + h)) * NCHUNK + c) * 64 + tid];
    __syncthreads();

    const int m4 = (tid & 15) * 4;   // m / e block
    const int lg = tid >> 4;         // l block: rows lg*4..+3
    // phase 1: P tile
    {
        float p[4][4] = {};
        for (int d = 0; d < 64; ++d) {
            const float4 k4 = *(const float4*)&sKt[d][m4];
            const float4 q4 = *(const float4*)&sQt[d][lg * 4];
            p[0][0] = fmaf(q4.x, k4.x, p[0][0]); p[0][1] = fmaf(q4.x, k4.y, p[0][1]);
            p[0][2] = fmaf(q4.x, k4.z, p[0][2]); p[0][3] = fmaf(q4.x, k4.w, p[0][3]);
            p[1][0] = fmaf(q4.y, k4.x, p[1][0]); p[1][1] = fmaf(q4.y, k4.y, p[1][1]);
            p[1][2] = fmaf(q4.y, k4.z, p[1][2]); p[1][3] = fmaf(q4.y, k4.w, p[1][3]);
            p[2][0] = fmaf(q4.z, k4.x, p[2][0]); p[2][1] = fmaf(q4.z, k4.y, p[2][1]);
            p[2][2] = fmaf(q4.z, k4.z, p[2][2]); p[2][3] = fmaf(q4.z, k4.w, p[2][3]);
            p[3][0] = fmaf(q4.w, k4.x, p[3][0]); p[3][1] = fmaf(q4.w, k4.y, p[3][1]);
            p[3][2] = fmaf(q4.w, k4.z, p[3][2]); p[3][3] = fmaf(q4.w, k4.w, p[3][3]);
        }
        #pragma unroll
        for (int jj = 0; jj < 4; ++jj)
            #pragma unroll
            for (int j = 0; j < 4; ++j)
                sPt[m4 + jj][lg * 4 + j] = p[j][jj];
    }
    __syncthreads();

    // phase 2
    float acc[4][4] = {};
    float z[4] = {};
    const int lmax = lg * 4 + 3;
    for (int m = 0; m <= lmax; ++m) {
        const float4 v4 = *(const float4*)&sV[m][m4];
        #pragma unroll
        for (int j = 0; j < 4; ++j) {
            const int l = lg * 4 + j;
            float p = sPt[m][l];
            p = (m <= l) ? p : 0.f;
            z[j] += p;
            acc[j][0] = fmaf(p, v4.x, acc[j][0]);
            acc[j][1] = fmaf(p, v4.y, acc[j][1]);
            acc[j][2] = fmaf(p, v4.z, acc[j][2]);
            acc[j][3] = fmaf(p, v4.w, acc[j][3]);
        }
    }
    for (int d = 0; d < 64; ++d) {
        const float4 s4 = *(const float4*)&sS[d][m4];
        const float4 q4 = *(const float4*)&sQt[d][lg * 4];
        const float kp = skp[d];
        z[0] = fmaf(q4.x, kp, z[0]); z[1] = fmaf(q4.y, kp, z[1]);
        z[2] = fmaf(q4.z, kp, z[2]); z[3] = fmaf(q4.w, kp, z[3]);
        acc[0][0] = fmaf(q4.x, s4.x, acc[0][0]); acc[0][1] = fmaf(q4.x, s4.y, acc[0][1]);
        acc[0][2] = fmaf(q4.x, s4.z, acc[0][2]); acc[0][3] = fmaf(q4.x, s4.w, acc[0][3]);
        acc[1][0] = fmaf(q4.y, s4.x, acc[1][0]); acc[1][1] = fmaf(q4.y, s4.y, acc[1][1]);
        acc[1][2] = fmaf(q4.y, s4.z, acc[1][2]); acc[1][3] = fmaf(q4.y, s4.w, acc[1][3]);
        acc[2][0] = fmaf(q4.z, s4.x, acc[2][0]); acc[2][1] = fmaf(q4.z, s4.y, acc[2][1]);
        acc[2][2] = fmaf(q4.z, s4.z, acc[2][2]); acc[2][3] = fmaf(q4.z, s4.w, acc[2][3]);
        acc[3][0] = fmaf(q4.w, s4.x, acc[3][0]); acc[3][1] = fmaf(q4.w, s4.y, acc[3][1]);
        acc[3][2] = fmaf(q4.w, s4.z, acc[3][2]); acc[3][3] = fmaf(q4.w, s4.w, acc[3][3]);
    }
    #pragma unroll
    for (int j = 0; j < 4; ++j) {
        const int l = lg * 4 + j;
        const float rz = 1.f / (z[j] + 1e-6f);
        const size_t ob = ((size_t)(n * LSEQ + c * 64 + l)) * DM + h * DKH + m4;
        O[ob + 0] = __float2bfloat16(acc[j][0] * rz);
        O[ob + 1] = __float2bfloat16(acc[j][1] * rz);
        O[ob + 2] = __float2bfloat16(acc[j][2] * rz);
        O[ob + 3] = __float2bfloat16(acc[j][3] * rz);
    }
}

// ---------------------------------------------------------------------------
extern "C" void kernel_launch(void* const* d_in, const int* in_sizes, int n_in,
                              void* d_out, int out_size, void* d_ws, size_t ws_size,
                              hipStream_t stream)
{
    const float* x_img   = (const float*)d_in[0];
    const int*   x_txt   = (const int*)  d_in[1];
    const float* mask_i  = (const float*)d_in[2];
    const float* mask_t  = (const float*)d_in[3];
    const float* pos_r   = (const float*)d_in[4];
    const float* pos_c   = (const float*)d_in[5];
    const float* pos_t   = (const float*)d_in[6];
    const float* W_ei    = (const float*)d_in[7];
    const float* b_ei    = (const float*)d_in[8];
    const float* emb_txt = (const float*)d_in[9];
    const float* Wq      = (const float*)d_in[10];
    const float* bq      = (const float*)d_in[11];
    const float* Wk      = (const float*)d_in[12];
    const float* bk      = (const float*)d_in[13];
    const float* Wv      = (const float*)d_in[14];
    const float* bv      = (const float*)d_in[15];
    const float* Wo      = (const float*)d_in[16];
    const float* bo      = (const float*)d_in[17];
    const float* W1      = (const float*)d_in[18];
    const float* b1      = (const float*)d_in[19];
    const float* W2      = (const float*)d_in[20];
    const float* b2      = (const float*)d_in[21];
    const float* ln1_s   = (const float*)d_in[22];
    const float* ln1_b   = (const float*)d_in[23];
    const float* ln2_s   = (const float*)d_in[24];
    const float* ln2_b   = (const float*)d_in[25];
    const float* W_pi    = (const float*)d_in[26];
    const float* b_pi    = (const float*)d_in[27];
    const float* W_pt    = (const float*)d_in[28];
    const float* b_pt    = (const float*)d_in[29];

    float* ws = (float*)d_ws;
    size_t off = 0;
    auto alloc = [&](size_t nfloats) { float* p = ws + off; off += nfloats; return p; };

    float* Xb   = alloc(1048576);           // activations fp32 (N,L,D)
    float* Yb   = alloc(1048576);           // residual-sum scratch
    float* QKVb = alloc(3145728);           // fused QKV fp32 (N,L,1536)
    float* Sb   = alloc(1048576);           // chunk KV sums -> prefixes
    float* ksb  = alloc(16384);
    float* qkvB = alloc(4 * QS);            // fused bias
    bf16* Xh    = (bf16*)alloc(524288);     // activations bf16
    bf16* Ob    = (bf16*)alloc(524288);     // attention out bf16
    bf16* Tb    = (bf16*)alloc(2097152);    // FF intermediate bf16 (N,L,FF)
    bf16* ximgh = (bf16*)alloc(524288);
    bf16* QKVt  = (bf16*)alloc(1572864);    // (NL,1536,512)
    bf16* Wot   = (bf16*)alloc(524288);     // (NL,512,512)
    bf16* W1t   = (bf16*)alloc(2097152);    // (NL,2048,512)
    bf16* W2t   = (bf16*)alloc(2097152);    // (NL,512,2048)
    bf16* Weit  = (bf16*)alloc(131072);     // (512,512)
    bf16* Wpit  = (bf16*)alloc(131072);     // (512,512)
    bf16* Wptt  = (bf16*)alloc(2097152);    // (8192,512) zero-padded

    const dim3 blk(256);
    const dim3 gAttn(NCHUNK, NHEAD, NB);

    // ---- weight casts ----
    cast_qkvo<<<dim3(16, 16, 16), blk, 0, stream>>>(Wq, Wk, Wv, Wo, QKVt, Wot);
    cast_t<<<dim3(64, 16, 4), blk, 0, stream>>>(W1, W1t, 512, 2048, 1048576, 1048576);
    cast_t<<<dim3(16, 64, 4), blk, 0, stream>>>(W2, W2t, 2048, 512, 1048576, 1048576);
    cast_small<<<dim3(16, 16, 2), blk, 0, stream>>>(W_ei, W_pi, Weit, Wpit);
    cast_t<<<dim3(256, 16, 1), blk, 0, stream>>>(W_pt, Wptt, 512, VOCAB, 0, 0);
    cast_e<<<dim3(1024), blk, 0, stream>>>(x_img, ximgh, 262144);
    qkv_bias_k<<<dim3(4), blk, 0, stream>>>(bq, bk, bv, qkvB);

    // ---- embedding ----
    gemm16<64, 64><<<dim3(8, 32), blk, 0, stream>>>(
        ximgh, Weit, b_ei, nullptr, Yb, nullptr, NROWS, 512, 512, OP_NONE);
    embed_k<<<NROWS, blk, 0, stream>>>(Yb, x_txt, emb_txt, mask_i, mask_t,
                                       pos_r, pos_c, pos_t, Xb, Xh);

    for (int i = 0; i < NLAYER; ++i) {
        // fused QKV projection (elu+1 on Q,K cols)
        gemm16<64, 128><<<dim3(12, 32), blk, 0, stream>>>(
            Xh, QKVt + (size_t)i * 786432, qkvB + i * QS, nullptr,
            QKVb, nullptr, NROWS, 512, QS, OP_QKV);

        attn_kv<<<gAttn, blk, 0, stream>>>(QKVb + 512, QKVb + 1024, Sb, ksb);
        attn_prefix<<<NB * NHEAD, blk, 0, stream>>>(Sb, ksb);
        attn_out<<<gAttn, blk, 0, stream>>>(QKVb, Sb, ksb, Ob);

        // out proj + residual -> LN1
        gemm16<64, 64><<<dim3(8, 32), blk, 0, stream>>>(
            Ob, Wot + (size_t)i * 262144, bo + (size_t)i * DM, Xb,
            Yb, nullptr, NROWS, 512, 512, OP_NONE);
        ln_k<<<NROWS, blk, 0, stream>>>(Yb, ln1_s + (size_t)i * DM,
                                        ln1_b + (size_t)i * DM, Xb, Xh);

        // FF
        gemm16<128, 128><<<dim3(16, 16), blk, 0, stream>>>(
            Xh, W1t + (size_t)i * 1048576, b1 + (size_t)i * FFD, nullptr,
            nullptr, Tb, NROWS, 512, FFD, OP_GELU);
        gemm16<64, 64><<<dim3(8, 32), blk, 0, stream>>>(
            Tb, W2t + (size_t)i * 1048576, b2 + (size_t)i * DM, Xb,
            Yb, nullptr, NROWS, 2048, 512, OP_NONE);
        ln_k<<<NROWS, blk, 0, stream>>>(Yb, ln2_s + (size_t)i * DM,
                                        ln2_b + (size_t)i * DM, Xb, Xh);
    }

    // ---- heads ----
    float* out = (float*)d_out;
    gemm16<64, 64><<<dim3(8, 32), blk, 0, stream>>>(
        Xh, Wpit, b_pi, nullptr, out, nullptr, NROWS, 512, 512, OP_NONE);
    gemm16<128, 256><<<dim3(32, 16), blk, 0, stream>>>(
        Xh, Wptt, b_pt, nullptr, out + 1048576, nullptr, NROWS, 512, VOCAB, OP_NONE);
}

// Round 4
// 702.800 us; speedup vs baseline: 1.8678x; 1.8678x over previous
//
#include <hip/hip_runtime.h>
#include <hip/hip_bf16.h>
#include <math.h>

// Model dims
#define NB 2
#define LSEQ 1024
#define DM 512
#define FFD 2048
#define NHEAD 8
#define DKH 64
#define NLAYER 4
#define VOCAB 8000
#define NCHUNK 16           // L / 64
#define NROWS (NB * LSEQ)   // 2048
#define QS 1536             // fused QKV row stride
#define NHEADCAT 8512       // 512 (img) + 8000 (txt)
#define NHEADPAD 8576       // padded to /128 (67*128)

#define OP_NONE 0
#define OP_GELU 2
#define OP_QKV  3   // elu+1 for col<1024 (Q,K), none for V
#define OP_PART 4   // raw fp32 partial at outF + z*M*Nout (split-K)
#define OP_HEAD 5   // col<512 -> outF (img, stride 512), else outF2 (txt, stride 8000)

typedef __attribute__((ext_vector_type(8))) short short8;
typedef __attribute__((ext_vector_type(4))) float f32x4;
typedef __hip_bfloat16 bf16;

// ---------------------------------------------------------------------------
// 32x32 transpose-cast tile body: src (K,N) fp32 -> dst (Npad,K) bf16.
// ---------------------------------------------------------------------------
__device__ __forceinline__ void cast_tile(
    const float* __restrict__ s, bf16* __restrict__ d, int K, int N,
    int n0, int k0, int tx, int ty)
{
    __shared__ float tile[32][33];
    #pragma unroll
    for (int i = 0; i < 4; ++i) {
        const int k = k0 + ty + 8 * i;
        const int n = n0 + tx;
        tile[ty + 8 * i][tx] = (n < N) ? s[(size_t)k * N + n] : 0.f;
    }
    __syncthreads();
    #pragma unroll
    for (int i = 0; i < 4; ++i) {
        const int n = n0 + ty + 8 * i;
        d[(size_t)n * K + k0 + tx] = __float2bfloat16(tile[tx][ty + 8 * i]);
    }
}

__global__ __launch_bounds__(256) void cast_t(
    const float* __restrict__ src, bf16* __restrict__ dst,
    int K, int N, size_t sStride, size_t dStride)
{
    const int z = blockIdx.z;
    cast_tile(src + (size_t)z * sStride, dst + (size_t)z * dStride, K, N,
              blockIdx.x * 32, blockIdx.y * 32,
              threadIdx.x & 31, threadIdx.x >> 5);
}

// Batched cast for Wq/Wk/Wv/Wo (all 512x512, 4 layers): z = layer*4 + which
__global__ __launch_bounds__(256) void cast_qkvo(
    const float* __restrict__ Wq, const float* __restrict__ Wk,
    const float* __restrict__ Wv, const float* __restrict__ Wo,
    bf16* __restrict__ QKVt, bf16* __restrict__ Wot)
{
    const int z = blockIdx.z, layer = z >> 2, which = z & 3;
    const float* src = (which == 0 ? Wq : which == 1 ? Wk : which == 2 ? Wv : Wo)
                       + (size_t)layer * 262144;
    bf16* dst = (which < 3) ? (QKVt + (size_t)layer * 786432 + (size_t)which * 262144)
                            : (Wot + (size_t)layer * 262144);
    cast_tile(src, dst, 512, 512, blockIdx.x * 32, blockIdx.y * 32,
              threadIdx.x & 31, threadIdx.x >> 5);
}

// Elementwise fp32 -> bf16 (layout preserved)
__global__ __launch_bounds__(256) void cast_e(
    const float* __restrict__ src, bf16* __restrict__ dst, int n4)
{
    const int i = blockIdx.x * 256 + threadIdx.x;
    if (i < n4) {
        const float4 v = *(const float4*)(src + (size_t)i * 4);
        dst[(size_t)i * 4 + 0] = __float2bfloat16(v.x);
        dst[(size_t)i * 4 + 1] = __float2bfloat16(v.y);
        dst[(size_t)i * 4 + 2] = __float2bfloat16(v.z);
        dst[(size_t)i * 4 + 3] = __float2bfloat16(v.w);
    }
}

// Build fused QKV bias (NL,1536)
__global__ __launch_bounds__(256) void qkv_bias_k(
    const float* __restrict__ bq, const float* __restrict__ bk,
    const float* __restrict__ bv, float* __restrict__ out)
{
    const int z = blockIdx.x;
    for (int j = threadIdx.x; j < QS; j += 256) {
        float v;
        if (j < 512)       v = bq[z * DM + j];
        else if (j < 1024) v = bk[z * DM + j - 512];
        else               v = bv[z * DM + j - 1024];
        out[z * QS + j] = v;
    }
}

// Concatenated head bias (512 img + 8000 txt + pad)
__global__ __launch_bounds__(256) void head_bias_k(
    const float* __restrict__ bpi, const float* __restrict__ bpt,
    float* __restrict__ hb)
{
    const int j = blockIdx.x * 256 + threadIdx.x;
    if (j < NHEADPAD)
        hb[j] = (j < 512) ? bpi[j] : (j < NHEADCAT ? bpt[j - 512] : 0.f);
}

// ---------------------------------------------------------------------------
// bf16 MFMA GEMM (m97 structure): C = op(A @ B + bias) [+ res]
// kslab: K-range per z-block (split-K when gridDim.z>1, op must be OP_PART).
// ---------------------------------------------------------------------------
template<int BM, int BN>
__global__ __launch_bounds__(256) void gemm16(
    const bf16* __restrict__ A, const bf16* __restrict__ Bt,
    const float* __restrict__ bias, const float* __restrict__ res,
    float* __restrict__ outF, float* __restrict__ outF2,
    bf16* __restrict__ outH,
    int M, int K, int Nout, int op, int kslab)
{
    constexpr int WM = BM / 2, WN = BN / 2, MI = WM / 16, NI = WN / 16;
    __shared__ bf16 As[BM * 32];
    __shared__ bf16 Bs[BN * 32];
    const int tid = threadIdx.x;
    const int lane = tid & 63;
    const int wave = tid >> 6;
    const int wm = (wave >> 1) * WM, wn = (wave & 1) * WN;
    const int bm = blockIdx.y * BM, bn = blockIdx.x * BN;
    const int l16 = lane & 15, quad = lane >> 4;

    const int rA = tid >> 2;
    const int c8 = (tid & 3) << 3;

    f32x4 acc[MI][NI];
    #pragma unroll
    for (int i = 0; i < MI; ++i)
        #pragma unroll
        for (int j = 0; j < NI; ++j) acc[i][j] = (f32x4){0.f, 0.f, 0.f, 0.f};

    const bf16* gA = A  + (size_t)(bm + rA) * K + c8;
    const bf16* gB = Bt + (size_t)(bn + rA) * K + c8;
    const int ldsWaveOff = wave * 1024;

    const int kStart = blockIdx.z * kslab;
    for (int k0 = kStart; k0 < kStart + kslab; k0 += 32) {
        __syncthreads();
        #pragma unroll
        for (int i = 0; i < BM / 64; ++i)
            __builtin_amdgcn_global_load_lds(
                (const __attribute__((address_space(1))) void*)(gA + (size_t)i * 64 * K + k0),
                (__attribute__((address_space(3))) void*)((char*)As + i * 4096 + ldsWaveOff),
                16, 0, 0);
        #pragma unroll
        for (int i = 0; i < BN / 64; ++i)
            __builtin_amdgcn_global_load_lds(
                (const __attribute__((address_space(1))) void*)(gB + (size_t)i * 64 * K + k0),
                (__attribute__((address_space(3))) void*)((char*)Bs + i * 4096 + ldsWaveOff),
                16, 0, 0);
        __syncthreads();
        short8 a[MI], b[NI];
        #pragma unroll
        for (int i = 0; i < MI; ++i)
            a[i] = *(const short8*)(As + (size_t)(wm + i * 16 + l16) * 32 + quad * 8);
        #pragma unroll
        for (int j = 0; j < NI; ++j)
            b[j] = *(const short8*)(Bs + (size_t)(wn + j * 16 + l16) * 32 + quad * 8);
        #pragma unroll
        for (int i = 0; i < MI; ++i)
            #pragma unroll
            for (int j = 0; j < NI; ++j)
                acc[i][j] = __builtin_amdgcn_mfma_f32_16x16x32_bf16(
                    a[i], b[j], acc[i][j], 0, 0, 0);
    }

    if (op == OP_PART) {
        float* dst = outF + (size_t)blockIdx.z * (size_t)M * Nout;
        #pragma unroll
        for (int j = 0; j < NI; ++j) {
            const int col = bn + wn + j * 16 + l16;
            #pragma unroll
            for (int i = 0; i < MI; ++i)
                #pragma unroll
                for (int r = 0; r < 4; ++r) {
                    const int row = bm + wm + i * 16 + quad * 4 + r;
                    dst[(size_t)row * Nout + col] = acc[i][j][r];
                }
        }
        return;
    }
    if (op == OP_HEAD) {
        #pragma unroll
        for (int j = 0; j < NI; ++j) {
            const int col = bn + wn + j * 16 + l16;
            const bool cok = (col < NHEADCAT);
            const float bz = cok ? bias[col] : 0.f;
            #pragma unroll
            for (int i = 0; i < MI; ++i)
                #pragma unroll
                for (int r = 0; r < 4; ++r) {
                    const int row = bm + wm + i * 16 + quad * 4 + r;
                    const float v = acc[i][j][r] + bz;
                    if (cok) {
                        if (col < 512) outF[(size_t)row * 512 + col] = v;
                        else           outF2[(size_t)row * VOCAB + (col - 512)] = v;
                    }
                }
        }
        return;
    }

    #pragma unroll
    for (int j = 0; j < NI; ++j) {
        const int col = bn + wn + j * 16 + l16;
        const bool cok = (col < Nout);
        const float bz = cok ? bias[col] : 0.f;
        #pragma unroll
        for (int i = 0; i < MI; ++i) {
            #pragma unroll
            for (int r = 0; r < 4; ++r) {
                const int row = bm + wm + i * 16 + quad * 4 + r;
                float v = acc[i][j][r] + bz;
                if (op == OP_GELU)      v = 0.5f * v * (1.f + erff(v * 0.70710678118654752f));
                else if (op == OP_QKV && col < 1024) v = (v > 0.f) ? v + 1.f : expf(v);
                if (cok) {
                    if (res)  v += res[(size_t)row * Nout + col];
                    if (outF) outF[(size_t)row * Nout + col] = v;
                    if (outH) outH[(size_t)row * Nout + col] = __float2bfloat16(v);
                }
            }
        }
    }
}

// ---------------------------------------------------------------------------
// Embedding combine. gI = x_img @ W_ei + b_ei (precomputed fp32).
// ---------------------------------------------------------------------------
__global__ __launch_bounds__(256) void embed_k(
    const float* __restrict__ gI, const int* __restrict__ xt,
    const float* __restrict__ emb,
    const float* __restrict__ mi, const float* __restrict__ mt,
    const float* __restrict__ pr, const float* __restrict__ pc,
    const float* __restrict__ pt, float* __restrict__ X, bf16* __restrict__ Xh)
{
    const int row = blockIdx.x;
    const float prv = pr[row], pcv = pc[row], ptv = pt[row];
    const float miv = mi[row], mtv = mt[row];
    const int tok = xt[row];
    const float LOG1E4 = 9.2103403719761836f;
    const float LI127 = LOG1E4 / 127.f;
    const float LI255 = LOG1E4 / 255.f;

    for (int d = threadIdx.x; d < DM; d += 256) {
        float ip;
        if (d < 128)       ip = sinf(prv * expf(-(float)d * LI127));
        else if (d < 256)  ip = cosf(prv * expf(-(float)(d - 128) * LI127));
        else if (d < 384)  ip = sinf(pcv * expf(-(float)(d - 256) * LI127));
        else               ip = cosf(pcv * expf(-(float)(d - 384) * LI127));
        float tp;
        if (d < 256) tp = sinf(ptv * expf(-(float)d * LI255));
        else         tp = cosf(ptv * expf(-(float)(d - 256) * LI255));
        const float v = miv * (gI[(size_t)row * DM + d] + ip)
                      + mtv * (emb[(size_t)tok * DM + d] + tp);
        X[(size_t)row * DM + d] = v;
        Xh[(size_t)row * DM + d] = __float2bfloat16(v);
    }
}

// ---------------------------------------------------------------------------
// Fused partial-sum + bias + residual + LayerNorm.
// y = res + bias + sum_{p<nP} P[p];  out = LN(y)*g + b  (fp32 + bf16).
// out may alias res: all reads precede the barrier-separated writes.
// ---------------------------------------------------------------------------
__global__ __launch_bounds__(256) void ln_red(
    const float* __restrict__ P, int nP,
    const float* __restrict__ bias, const float* __restrict__ res,
    const float* __restrict__ g, const float* __restrict__ b,
    float* __restrict__ out, bf16* __restrict__ outh)
{
    const int row = blockIdx.x;
    const int tid = threadIdx.x;
    const size_t base = (size_t)row * DM;
    float x0 = res[base + tid] + bias[tid];
    float x1 = res[base + tid + 256] + bias[tid + 256];
    for (int p = 0; p < nP; ++p) {
        x0 += P[(size_t)p * 1048576 + base + tid];
        x1 += P[(size_t)p * 1048576 + base + tid + 256];
    }
    __shared__ float red[256];
    red[tid] = x0 + x1;
    __syncthreads();
    for (int off = 128; off > 0; off >>= 1) {
        if (tid < off) red[tid] += red[tid + off];
        __syncthreads();
    }
    const float mean = red[0] / (float)DM;
    __syncthreads();
    const float d0 = x0 - mean, d1 = x1 - mean;
    red[tid] = d0 * d0 + d1 * d1;
    __syncthreads();
    for (int off = 128; off > 0; off >>= 1) {
        if (tid < off) red[tid] += red[tid + off];
        __syncthreads();
    }
    const float var = red[0] / (float)DM;
    const float rstd = rsqrtf(var + 1e-5f);
    const float y0 = d0 * rstd * g[tid] + b[tid];
    const float y1 = d1 * rstd * g[tid + 256] + b[tid + 256];
    out[base + tid]        = y0;
    out[base + tid + 256]  = y1;
    outh[base + tid]       = __float2bfloat16(y0);
    outh[base + tid + 256] = __float2bfloat16(y1);
}

// ---------------------------------------------------------------------------
// Chunked-parallel linear attention.
// Kernel 1: S_c = K_c^T @ V_c (64x64) and ksum_c. Grid (16,8,2).
// ---------------------------------------------------------------------------
__global__ __launch_bounds__(256) void attn_kv(
    const float* __restrict__ Kp, const float* __restrict__ Vp,
    float* __restrict__ S, float* __restrict__ ks)
{
    const int c = blockIdx.x, h = blockIdx.y, n = blockIdx.z;
    const int tid = threadIdx.x;
    __shared__ float sK[64][64], sV[64][64], part[4][64];

    const int lr = tid >> 4;
    const int c4 = (tid & 15) * 4;
    #pragma unroll
    for (int it = 0; it < 4; ++it) {
        const int row = it * 16 + lr;
        const size_t gb = ((size_t)(n * LSEQ + c * 64 + row)) * QS + h * DKH + c4;
        *(float4*)&sK[row][c4] = *(const float4*)(Kp + gb);
        *(float4*)&sV[row][c4] = *(const float4*)(Vp + gb);
    }
    __syncthreads();

    const int e = tid & 63, dq = tid >> 6;
    float s[16] = {};
    for (int l = 0; l < 64; ++l) {
        const float vv = sV[l][e];
        const float4 k0 = *(const float4*)&sK[l][dq * 16 + 0];
        const float4 k1 = *(const float4*)&sK[l][dq * 16 + 4];
        const float4 k2 = *(const float4*)&sK[l][dq * 16 + 8];
        const float4 k3 = *(const float4*)&sK[l][dq * 16 + 12];
        s[0]  = fmaf(k0.x, vv, s[0]);  s[1]  = fmaf(k0.y, vv, s[1]);
        s[2]  = fmaf(k0.z, vv, s[2]);  s[3]  = fmaf(k0.w, vv, s[3]);
        s[4]  = fmaf(k1.x, vv, s[4]);  s[5]  = fmaf(k1.y, vv, s[5]);
        s[6]  = fmaf(k1.z, vv, s[6]);  s[7]  = fmaf(k1.w, vv, s[7]);
        s[8]  = fmaf(k2.x, vv, s[8]);  s[9]  = fmaf(k2.y, vv, s[9]);
        s[10] = fmaf(k2.z, vv, s[10]); s[11] = fmaf(k2.w, vv, s[11]);
        s[12] = fmaf(k3.x, vv, s[12]); s[13] = fmaf(k3.y, vv, s[13]);
        s[14] = fmaf(k3.z, vv, s[14]); s[15] = fmaf(k3.w, vv, s[15]);
    }
    const size_t sb = (((size_t)(n * NHEAD + h)) * NCHUNK + c) * 4096;
    #pragma unroll
    for (int i = 0; i < 16; ++i) S[sb + (size_t)(dq * 16 + i) * 64 + e] = s[i];

    float kp = 0.f;
    #pragma unroll
    for (int i = 0; i < 16; ++i) kp += sK[dq * 16 + i][e];
    part[dq][e] = kp;
    __syncthreads();
    if (tid < 64)
        ks[(((size_t)(n * NHEAD + h)) * NCHUNK + c) * 64 + tid] =
            part[0][tid] + part[1][tid] + part[2][tid] + part[3][tid];
}

// Kernel 2: exclusive prefix over chunks, fully parallel over state index.
// Grid 256 blocks x 256 thr = 65536 = 16 nh-groups * 4096 state elems.
__global__ __launch_bounds__(256) void attn_prefix(
    float* __restrict__ S, float* __restrict__ ks)
{
    const int gid = blockIdx.x * 256 + threadIdx.x;
    const int nh = gid >> 12, j = gid & 4095;
    const size_t base = ((size_t)nh * NCHUNK) * 4096 + j;
    float run = 0.f;
    #pragma unroll
    for (int c = 0; c < NCHUNK; ++c) {
        const float t = S[base + (size_t)c * 4096];
        S[base + (size_t)c * 4096] = run;
        run += t;
    }
    if (gid < NB * NHEAD * 64) {
        const int nh2 = gid >> 6, j2 = gid & 63;
        const size_t kb = ((size_t)nh2 * NCHUNK) * 64 + j2;
        float kr = 0.f;
        #pragma unroll
        for (int c = 0; c < NCHUNK; ++c) {
            const float t = ks[kb + c * 64];
            ks[kb + c * 64] = kr;
            kr += t;
        }
    }
}

// Kernel 3: O = Q@S_pre + tril(Q@K^T)@V, Z = Q.kpre + rowsum(tril(QK^T)).
__global__ __launch_bounds__(256) void attn_out(
    const float* __restrict__ QKV, const float* __restrict__ S,
    const float* __restrict__ ks, bf16* __restrict__ O)
{
    const int c = blockIdx.x, h = blockIdx.y, n = blockIdx.z;
    const int tid = threadIdx.x;
    __shared__ float sQt[64][64];
    __shared__ float sKt[64][64];
    __shared__ float sV [64][64];
    __shared__ float sS [64][64];
    __shared__ float sPt[64][65];
    __shared__ float skp[64];

    const int lr = tid >> 4;
    const int c4 = (tid & 15) * 4;
    const size_t sb = (((size_t)(n * NHEAD + h)) * NCHUNK + c) * 4096;
    #pragma unroll
    for (int it = 0; it < 4; ++it) {
        const int row = it * 16 + lr;
        const size_t gb = ((size_t)(n * LSEQ + c * 64 + row)) * QS + h * DKH + c4;
        const float4 q4 = *(const float4*)(QKV + gb);
        const float4 k4 = *(const float4*)(QKV + gb + 512);
        const float4 v4 = *(const float4*)(QKV + gb + 1024);
        sQt[c4 + 0][row] = q4.x; sQt[c4 + 1][row] = q4.y;
        sQt[c4 + 2][row] = q4.z; sQt[c4 + 3][row] = q4.w;
        sKt[c4 + 0][row] = k4.x; sKt[c4 + 1][row] = k4.y;
        sKt[c4 + 2][row] = k4.z; sKt[c4 + 3][row] = k4.w;
        *(float4*)&sV[row][c4] = v4;
        *(float4*)&sS[row][c4] = *(const float4*)(S + sb + (size_t)row * 64 + c4);
    }
    if (tid < 64) skp[tid] = ks[(((size_t)(n * NHEAD + h)) * NCHUNK + c) * 64 + tid];
    __syncthreads();

    const int m4 = (tid & 15) * 4;
    const int lg = tid >> 4;
    {
        float p[4][4] = {};
        for (int d = 0; d < 64; ++d) {
            const float4 k4 = *(const float4*)&sKt[d][m4];
            const float4 q4 = *(const float4*)&sQt[d][lg * 4];
            p[0][0] = fmaf(q4.x, k4.x, p[0][0]); p[0][1] = fmaf(q4.x, k4.y, p[0][1]);
            p[0][2] = fmaf(q4.x, k4.z, p[0][2]); p[0][3] = fmaf(q4.x, k4.w, p[0][3]);
            p[1][0] = fmaf(q4.y, k4.x, p[1][0]); p[1][1] = fmaf(q4.y, k4.y, p[1][1]);
            p[1][2] = fmaf(q4.y, k4.z, p[1][2]); p[1][3] = fmaf(q4.y, k4.w, p[1][3]);
            p[2][0] = fmaf(q4.z, k4.x, p[2][0]); p[2][1] = fmaf(q4.z, k4.y, p[2][1]);
            p[2][2] = fmaf(q4.z, k4.z, p[2][2]); p[2][3] = fmaf(q4.z, k4.w, p[2][3]);
            p[3][0] = fmaf(q4.w, k4.x, p[3][0]); p[3][1] = fmaf(q4.w, k4.y, p[3][1]);
            p[3][2] = fmaf(q4.w, k4.z, p[3][2]); p[3][3] = fmaf(q4.w, k4.w, p[3][3]);
        }
        #pragma unroll
        for (int jj = 0; jj < 4; ++jj)
            #pragma unroll
            for (int j = 0; j < 4; ++j)
                sPt[m4 + jj][lg * 4 + j] = p[j][jj];
    }
    __syncthreads();

    float acc[4][4] = {};
    float z[4] = {};
    const int lmax = lg * 4 + 3;
    for (int m = 0; m <= lmax; ++m) {
        const float4 v4 = *(const float4*)&sV[m][m4];
        #pragma unroll
        for (int j = 0; j < 4; ++j) {
            const int l = lg * 4 + j;
            float p = sPt[m][l];
            p = (m <= l) ? p : 0.f;
            z[j] += p;
            acc[j][0] = fmaf(p, v4.x, acc[j][0]);
            acc[j][1] = fmaf(p, v4.y, acc[j][1]);
            acc[j][2] = fmaf(p, v4.z, acc[j][2]);
            acc[j][3] = fmaf(p, v4.w, acc[j][3]);
        }
    }
    for (int d = 0; d < 64; ++d) {
        const float4 s4 = *(const float4*)&sS[d][m4];
        const float4 q4 = *(const float4*)&sQt[d][lg * 4];
        const float kp = skp[d];
        z[0] = fmaf(q4.x, kp, z[0]); z[1] = fmaf(q4.y, kp, z[1]);
        z[2] = fmaf(q4.z, kp, z[2]); z[3] = fmaf(q4.w, kp, z[3]);
        acc[0][0] = fmaf(q4.x, s4.x, acc[0][0]); acc[0][1] = fmaf(q4.x, s4.y, acc[0][1]);
        acc[0][2] = fmaf(q4.x, s4.z, acc[0][2]); acc[0][3] = fmaf(q4.x, s4.w, acc[0][3]);
        acc[1][0] = fmaf(q4.y, s4.x, acc[1][0]); acc[1][1] = fmaf(q4.y, s4.y, acc[1][1]);
        acc[1][2] = fmaf(q4.y, s4.z, acc[1][2]); acc[1][3] = fmaf(q4.y, s4.w, acc[1][3]);
        acc[2][0] = fmaf(q4.z, s4.x, acc[2][0]); acc[2][1] = fmaf(q4.z, s4.y, acc[2][1]);
        acc[2][2] = fmaf(q4.z, s4.z, acc[2][2]); acc[2][3] = fmaf(q4.z, s4.w, acc[2][3]);
        acc[3][0] = fmaf(q4.w, s4.x, acc[3][0]); acc[3][1] = fmaf(q4.w, s4.y, acc[3][1]);
        acc[3][2] = fmaf(q4.w, s4.z, acc[3][2]); acc[3][3] = fmaf(q4.w, s4.w, acc[3][3]);
    }
    #pragma unroll
    for (int j = 0; j < 4; ++j) {
        const int l = lg * 4 + j;
        const float rz = 1.f / (z[j] + 1e-6f);
        const size_t ob = ((size_t)(n * LSEQ + c * 64 + l)) * DM + h * DKH + m4;
        O[ob + 0] = __float2bfloat16(acc[j][0] * rz);
        O[ob + 1] = __float2bfloat16(acc[j][1] * rz);
        O[ob + 2] = __float2bfloat16(acc[j][2] * rz);
        O[ob + 3] = __float2bfloat16(acc[j][3] * rz);
    }
}

// ---------------------------------------------------------------------------
extern "C" void kernel_launch(void* const* d_in, const int* in_sizes, int n_in,
                              void* d_out, int out_size, void* d_ws, size_t ws_size,
                              hipStream_t stream)
{
    const float* x_img   = (const float*)d_in[0];
    const int*   x_txt   = (const int*)  d_in[1];
    const float* mask_i  = (const float*)d_in[2];
    const float* mask_t  = (const float*)d_in[3];
    const float* pos_r   = (const float*)d_in[4];
    const float* pos_c   = (const float*)d_in[5];
    const float* pos_t   = (const float*)d_in[6];
    const float* W_ei    = (const float*)d_in[7];
    const float* b_ei    = (const float*)d_in[8];
    const float* emb_txt = (const float*)d_in[9];
    const float* Wq      = (const float*)d_in[10];
    const float* bq      = (const float*)d_in[11];
    const float* Wk      = (const float*)d_in[12];
    const float* bk      = (const float*)d_in[13];
    const float* Wv      = (const float*)d_in[14];
    const float* bv      = (const float*)d_in[15];
    const float* Wo      = (const float*)d_in[16];
    const float* bo      = (const float*)d_in[17];
    const float* W1      = (const float*)d_in[18];
    const float* b1      = (const float*)d_in[19];
    const float* W2      = (const float*)d_in[20];
    const float* b2      = (const float*)d_in[21];
    const float* ln1_s   = (const float*)d_in[22];
    const float* ln1_b   = (const float*)d_in[23];
    const float* ln2_s   = (const float*)d_in[24];
    const float* ln2_b   = (const float*)d_in[25];
    const float* W_pi    = (const float*)d_in[26];
    const float* b_pi    = (const float*)d_in[27];
    const float* W_pt    = (const float*)d_in[28];
    const float* b_pt    = (const float*)d_in[29];

    float* ws = (float*)d_ws;
    size_t off = 0;
    auto alloc = [&](size_t nfloats) { float* p = ws + off; off += nfloats; return p; };

    float* Xb   = alloc(1048576);           // activations fp32 (N,L,D)
    float* Pb   = alloc(4194304);           // split-K partials (up to 4) / embed scratch
    float* QKVb = alloc(3145728);           // fused QKV fp32 (N,L,1536)
    float* Sb   = alloc(1048576);           // chunk KV sums -> prefixes
    float* ksb  = alloc(16384);
    float* qkvB = alloc(4 * QS);            // fused QKV bias
    float* hb   = alloc(8704);              // concat head bias
    bf16* Xh    = (bf16*)alloc(524288);     // activations bf16
    bf16* Ob    = (bf16*)alloc(524288);     // attention out bf16
    bf16* Tb    = (bf16*)alloc(2097152);    // FF intermediate bf16 (N,L,FF)
    bf16* ximgh = (bf16*)alloc(524288);
    bf16* QKVt  = (bf16*)alloc(1572864);    // (NL,1536,512)
    bf16* Wot   = (bf16*)alloc(524288);     // (NL,512,512)
    bf16* W1t   = (bf16*)alloc(2097152);    // (NL,2048,512)
    bf16* W2t   = (bf16*)alloc(2097152);    // (NL,512,2048)
    bf16* Weit  = (bf16*)alloc(131072);     // (512,512)
    bf16* Whead = (bf16*)alloc(2195456);    // (8576,512): W_pi rows 0..511, W_pt 512..8511

    const dim3 blk(256);
    const dim3 gAttn(NCHUNK, NHEAD, NB);

    // ---- weight casts ----
    cast_qkvo<<<dim3(16, 16, 16), blk, 0, stream>>>(Wq, Wk, Wv, Wo, QKVt, Wot);
    cast_t<<<dim3(64, 16, 4), blk, 0, stream>>>(W1, W1t, 512, 2048, 1048576, 1048576);
    cast_t<<<dim3(16, 64, 4), blk, 0, stream>>>(W2, W2t, 2048, 512, 1048576, 1048576);
    cast_t<<<dim3(16, 16, 1), blk, 0, stream>>>(W_ei, Weit, 512, 512, 0, 0);
    cast_t<<<dim3(16, 16, 1), blk, 0, stream>>>(W_pi, Whead, 512, 512, 0, 0);
    cast_t<<<dim3(252, 16, 1), blk, 0, stream>>>(W_pt, Whead + 262144, 512, VOCAB, 0, 0);
    cast_e<<<dim3(1024), blk, 0, stream>>>(x_img, ximgh, 262144);
    qkv_bias_k<<<dim3(4), blk, 0, stream>>>(bq, bk, bv, qkvB);
    head_bias_k<<<dim3(34), blk, 0, stream>>>(b_pi, b_pt, hb);

    // ---- embedding ----
    gemm16<64, 64><<<dim3(8, 32), blk, 0, stream>>>(
        ximgh, Weit, b_ei, nullptr, Pb, nullptr, nullptr, NROWS, 512, 512, OP_NONE, 512);
    embed_k<<<NROWS, blk, 0, stream>>>(Pb, x_txt, emb_txt, mask_i, mask_t,
                                       pos_r, pos_c, pos_t, Xb, Xh);

    for (int i = 0; i < NLAYER; ++i) {
        // fused QKV projection (elu+1 on Q,K cols)
        gemm16<64, 128><<<dim3(12, 32), blk, 0, stream>>>(
            Xh, QKVt + (size_t)i * 786432, qkvB + i * QS, nullptr,
            QKVb, nullptr, nullptr, NROWS, 512, QS, OP_QKV, 512);

        attn_kv<<<gAttn, blk, 0, stream>>>(QKVb + 512, QKVb + 1024, Sb, ksb);
        attn_prefix<<<dim3(256), blk, 0, stream>>>(Sb, ksb);
        attn_out<<<gAttn, blk, 0, stream>>>(QKVb, Sb, ksb, Ob);

        // out proj (split-K=2 partials) -> fused reduce+residual+LN1
        gemm16<64, 64><<<dim3(8, 32, 2), blk, 0, stream>>>(
            Ob, Wot + (size_t)i * 262144, nullptr, nullptr,
            Pb, nullptr, nullptr, NROWS, 512, 512, OP_PART, 256);
        ln_red<<<NROWS, blk, 0, stream>>>(Pb, 2, bo + (size_t)i * DM, Xb,
                                          ln1_s + (size_t)i * DM,
                                          ln1_b + (size_t)i * DM, Xb, Xh);

        // FF1 (gelu fused) -> FF2 (split-K=4) -> fused reduce+residual+LN2
        gemm16<128, 128><<<dim3(16, 16), blk, 0, stream>>>(
            Xh, W1t + (size_t)i * 1048576, b1 + (size_t)i * FFD, nullptr,
            nullptr, nullptr, Tb, NROWS, 512, FFD, OP_GELU, 512);
        gemm16<64, 64><<<dim3(8, 32, 4), blk, 0, stream>>>(
            Tb, W2t + (size_t)i * 1048576, nullptr, nullptr,
            Pb, nullptr, nullptr, NROWS, 2048, 512, OP_PART, 512);
        ln_red<<<NROWS, blk, 0, stream>>>(Pb, 4, b2 + (size_t)i * DM, Xb,
                                          ln2_s + (size_t)i * DM,
                                          ln2_b + (size_t)i * DM, Xb, Xh);
    }

    // ---- merged heads: [logit_img | logit_txt] in one GEMM ----
    float* out = (float*)d_out;
    gemm16<128, 128><<<dim3(67, 16), blk, 0, stream>>>(
        Xh, Whead, hb, nullptr, out, out + 1048576, nullptr,
        NROWS, 512, NHEADCAT, OP_HEAD, 512);
}

// Round 5
// 650.870 us; speedup vs baseline: 2.0168x; 1.0798x over previous
//
#include <hip/hip_runtime.h>
#include <hip/hip_bf16.h>
#include <math.h>

// Model dims
#define NB 2
#define LSEQ 1024
#define DM 512
#define FFD 2048
#define NHEAD 8
#define DKH 64
#define NLAYER 4
#define VOCAB 8000
#define NCHUNK 16           // L / 64
#define NROWS (NB * LSEQ)   // 2048
#define QS 1536             // fused QKV row stride
#define NHEADCAT 8512       // 512 (img) + 8000 (txt)
#define NHEADPAD 8576       // padded: 512 + 252*32

#define OP_NONE 0
#define OP_GELU 2
#define OP_QKV  3   // elu+1 for col<1024 (Q,K), none for V
#define OP_PART 4   // raw fp32 partial at outF + z*M*Nout (split-K)
#define OP_HEAD 5   // col<512 -> outF (img), else outF2 (txt); grid x=M-tiles!

typedef __attribute__((ext_vector_type(8))) short short8;
typedef __attribute__((ext_vector_type(4))) float f32x4;
typedef __hip_bfloat16 bf16;

// ---------------------------------------------------------------------------
// 32x32 transpose-cast tile: src (K,N) fp32 -> dst (Npad,K) bf16; n>=N -> 0.
// ---------------------------------------------------------------------------
__device__ __forceinline__ void cast_tile(
    const float* __restrict__ s, bf16* __restrict__ d, int K, int N,
    int n0, int k0, int tx, int ty)
{
    __shared__ float tile[32][33];
    #pragma unroll
    for (int i = 0; i < 4; ++i) {
        const int k = k0 + ty + 8 * i;
        const int n = n0 + tx;
        tile[ty + 8 * i][tx] = (n < N) ? s[(size_t)k * N + n] : 0.f;
    }
    __syncthreads();
    #pragma unroll
    for (int i = 0; i < 4; ++i) {
        const int n = n0 + ty + 8 * i;
        d[(size_t)n * K + k0 + tx] = __float2bfloat16(tile[tx][ty + 8 * i]);
    }
}

// ---------------------------------------------------------------------------
// ONE setup dispatch: all weight transposes-casts, x_img cast, bias prep.
// Flat-grid block ranges (see offsets below).
// ---------------------------------------------------------------------------
#define CO_QKVO 0        // 4096: Wq/Wk/Wv/Wo (4 layers x 4 x 256 tiles)
#define CO_W1   4096     // 4096
#define CO_W2   8192     // 4096
#define CO_WEI  12288    // 256
#define CO_WPI  12544    // 256
#define CO_WPT  12800    // 4032
#define CO_XIMG 16832    // 1024
#define CO_QKVB 17856    // 4
#define CO_HB   17860    // 34
#define CO_END  17894

__global__ __launch_bounds__(256) void setup_all(
    const float* __restrict__ Wq, const float* __restrict__ Wk,
    const float* __restrict__ Wv, const float* __restrict__ Wo,
    const float* __restrict__ W1, const float* __restrict__ W2,
    const float* __restrict__ Wei, const float* __restrict__ Wpi,
    const float* __restrict__ Wpt,
    bf16* __restrict__ QKVt, bf16* __restrict__ Wot,
    bf16* __restrict__ W1t, bf16* __restrict__ W2t,
    bf16* __restrict__ Weit, bf16* __restrict__ Whead,
    const float* __restrict__ x_img, bf16* __restrict__ ximgh,
    const float* __restrict__ bq, const float* __restrict__ bk,
    const float* __restrict__ bv, float* __restrict__ qkvB,
    const float* __restrict__ bpi, const float* __restrict__ bpt,
    float* __restrict__ hb)
{
    const int id = blockIdx.x;
    const int tid = threadIdx.x;
    const int tx = tid & 31, ty = tid >> 5;

    if (id < CO_W1) {                       // QKVO 512x512 casts
        const int rel = id;
        const int z = rel >> 8, t = rel & 255;
        const int layer = z >> 2, which = z & 3;
        const float* src = (which == 0 ? Wq : which == 1 ? Wk : which == 2 ? Wv : Wo)
                           + (size_t)layer * 262144;
        bf16* dst = (which < 3)
            ? (QKVt + (size_t)layer * 786432 + (size_t)which * 262144)
            : (Wot + (size_t)layer * 262144);
        cast_tile(src, dst, 512, 512, (t & 15) * 32, (t >> 4) * 32, tx, ty);
    } else if (id < CO_W2) {                // W1 (512,2048) x4
        const int rel = id - CO_W1;
        const int z = rel >> 10, t = rel & 1023;
        cast_tile(W1 + (size_t)z * 1048576, W1t + (size_t)z * 1048576,
                  512, 2048, (t & 63) * 32, (t >> 6) * 32, tx, ty);
    } else if (id < CO_WEI) {               // W2 (2048,512) x4
        const int rel = id - CO_W2;
        const int z = rel >> 10, t = rel & 1023;
        cast_tile(W2 + (size_t)z * 1048576, W2t + (size_t)z * 1048576,
                  2048, 512, (t & 15) * 32, (t >> 4) * 32, tx, ty);
    } else if (id < CO_WPI) {               // W_ei
        const int t = id - CO_WEI;
        cast_tile(Wei, Weit, 512, 512, (t & 15) * 32, (t >> 4) * 32, tx, ty);
    } else if (id < CO_WPT) {               // W_pi -> Whead rows 0..511
        const int t = id - CO_WPI;
        cast_tile(Wpi, Whead, 512, 512, (t & 15) * 32, (t >> 4) * 32, tx, ty);
    } else if (id < CO_XIMG) {              // W_pt -> Whead rows 512..8575
        const int t = id - CO_WPT;
        cast_tile(Wpt, Whead + 262144, 512, VOCAB,
                  (t % 252) * 32, (t / 252) * 32, tx, ty);
    } else if (id < CO_QKVB) {              // x_img elementwise cast
        const int i = (id - CO_XIMG) * 256 + tid;   // i < 262144 (x4 floats)
        const float4 v = *(const float4*)(x_img + (size_t)i * 4);
        ximgh[(size_t)i * 4 + 0] = __float2bfloat16(v.x);
        ximgh[(size_t)i * 4 + 1] = __float2bfloat16(v.y);
        ximgh[(size_t)i * 4 + 2] = __float2bfloat16(v.z);
        ximgh[(size_t)i * 4 + 3] = __float2bfloat16(v.w);
    } else if (id < CO_HB) {                // fused QKV bias, one layer per block
        const int z = id - CO_QKVB;
        for (int j = tid; j < QS; j += 256) {
            float v;
            if (j < 512)       v = bq[z * DM + j];
            else if (j < 1024) v = bk[z * DM + j - 512];
            else               v = bv[z * DM + j - 1024];
            qkvB[z * QS + j] = v;
        }
    } else {                                // concat head bias
        const int j = (id - CO_HB) * 256 + tid;
        if (j < NHEADPAD)
            hb[j] = (j < 512) ? bpi[j] : (j < NHEADCAT ? bpt[j - 512] : 0.f);
    }
}

// ---------------------------------------------------------------------------
// bf16 MFMA GEMM (m97 structure): C = op(A @ B + bias) [+ res]
// kslab: K-range per z-block (split-K when gridDim.z>1, op must be OP_PART).
// OP_HEAD uses transposed grid mapping (x = M-tiles) for B-tile L2 reuse.
// ---------------------------------------------------------------------------
template<int BM, int BN>
__global__ __launch_bounds__(256) void gemm16(
    const bf16* __restrict__ A, const bf16* __restrict__ Bt,
    const float* __restrict__ bias, const float* __restrict__ res,
    float* __restrict__ outF, float* __restrict__ outF2,
    bf16* __restrict__ outH,
    int M, int K, int Nout, int op, int kslab)
{
    constexpr int WM = BM / 2, WN = BN / 2, MI = WM / 16, NI = WN / 16;
    __shared__ bf16 As[BM * 32];
    __shared__ bf16 Bs[BN * 32];
    const int tid = threadIdx.x;
    const int lane = tid & 63;
    const int wave = tid >> 6;
    const int wm = (wave >> 1) * WM, wn = (wave & 1) * WN;
    const int bm = (op == OP_HEAD ? blockIdx.x : blockIdx.y) * BM;
    const int bn = (op == OP_HEAD ? blockIdx.y : blockIdx.x) * BN;
    const int l16 = lane & 15, quad = lane >> 4;

    const int rA = tid >> 2;
    const int c8 = (tid & 3) << 3;

    f32x4 acc[MI][NI];
    #pragma unroll
    for (int i = 0; i < MI; ++i)
        #pragma unroll
        for (int j = 0; j < NI; ++j) acc[i][j] = (f32x4){0.f, 0.f, 0.f, 0.f};

    const bf16* gA = A  + (size_t)(bm + rA) * K + c8;
    const bf16* gB = Bt + (size_t)(bn + rA) * K + c8;
    const int ldsWaveOff = wave * 1024;

    const int kStart = blockIdx.z * kslab;
    for (int k0 = kStart; k0 < kStart + kslab; k0 += 32) {
        __syncthreads();
        #pragma unroll
        for (int i = 0; i < BM / 64; ++i)
            __builtin_amdgcn_global_load_lds(
                (const __attribute__((address_space(1))) void*)(gA + (size_t)i * 64 * K + k0),
                (__attribute__((address_space(3))) void*)((char*)As + i * 4096 + ldsWaveOff),
                16, 0, 0);
        #pragma unroll
        for (int i = 0; i < BN / 64; ++i)
            __builtin_amdgcn_global_load_lds(
                (const __attribute__((address_space(1))) void*)(gB + (size_t)i * 64 * K + k0),
                (__attribute__((address_space(3))) void*)((char*)Bs + i * 4096 + ldsWaveOff),
                16, 0, 0);
        __syncthreads();
        short8 a[MI], b[NI];
        #pragma unroll
        for (int i = 0; i < MI; ++i)
            a[i] = *(const short8*)(As + (size_t)(wm + i * 16 + l16) * 32 + quad * 8);
        #pragma unroll
        for (int j = 0; j < NI; ++j)
            b[j] = *(const short8*)(Bs + (size_t)(wn + j * 16 + l16) * 32 + quad * 8);
        #pragma unroll
        for (int i = 0; i < MI; ++i)
            #pragma unroll
            for (int j = 0; j < NI; ++j)
                acc[i][j] = __builtin_amdgcn_mfma_f32_16x16x32_bf16(
                    a[i], b[j], acc[i][j], 0, 0, 0);
    }

    if (op == OP_PART) {
        float* dst = outF + (size_t)blockIdx.z * (size_t)M * Nout;
        #pragma unroll
        for (int j = 0; j < NI; ++j) {
            const int col = bn + wn + j * 16 + l16;
            #pragma unroll
            for (int i = 0; i < MI; ++i)
                #pragma unroll
                for (int r = 0; r < 4; ++r) {
                    const int row = bm + wm + i * 16 + quad * 4 + r;
                    dst[(size_t)row * Nout + col] = acc[i][j][r];
                }
        }
        return;
    }
    if (op == OP_HEAD) {
        #pragma unroll
        for (int j = 0; j < NI; ++j) {
            const int col = bn + wn + j * 16 + l16;
            const bool cok = (col < NHEADCAT);
            const float bz = cok ? bias[col] : 0.f;
            #pragma unroll
            for (int i = 0; i < MI; ++i)
                #pragma unroll
                for (int r = 0; r < 4; ++r) {
                    const int row = bm + wm + i * 16 + quad * 4 + r;
                    const float v = acc[i][j][r] + bz;
                    if (cok) {
                        if (col < 512) outF[(size_t)row * 512 + col] = v;
                        else           outF2[(size_t)row * VOCAB + (col - 512)] = v;
                    }
                }
        }
        return;
    }

    #pragma unroll
    for (int j = 0; j < NI; ++j) {
        const int col = bn + wn + j * 16 + l16;
        const bool cok = (col < Nout);
        const float bz = cok ? bias[col] : 0.f;
        #pragma unroll
        for (int i = 0; i < MI; ++i) {
            #pragma unroll
            for (int r = 0; r < 4; ++r) {
                const int row = bm + wm + i * 16 + quad * 4 + r;
                float v = acc[i][j][r] + bz;
                if (op == OP_GELU)      v = 0.5f * v * (1.f + erff(v * 0.70710678118654752f));
                else if (op == OP_QKV && col < 1024) v = (v > 0.f) ? v + 1.f : expf(v);
                if (cok) {
                    if (res)  v += res[(size_t)row * Nout + col];
                    if (outF) outF[(size_t)row * Nout + col] = v;
                    if (outH) outH[(size_t)row * Nout + col] = __float2bfloat16(v);
                }
            }
        }
    }
}

// ---------------------------------------------------------------------------
// Embedding combine. gI = x_img @ W_ei + b_ei (precomputed fp32).
// ---------------------------------------------------------------------------
__global__ __launch_bounds__(256) void embed_k(
    const float* __restrict__ gI, const int* __restrict__ xt,
    const float* __restrict__ emb,
    const float* __restrict__ mi, const float* __restrict__ mt,
    const float* __restrict__ pr, const float* __restrict__ pc,
    const float* __restrict__ pt, float* __restrict__ X, bf16* __restrict__ Xh)
{
    const int row = blockIdx.x;
    const float prv = pr[row], pcv = pc[row], ptv = pt[row];
    const float miv = mi[row], mtv = mt[row];
    const int tok = xt[row];
    const float LOG1E4 = 9.2103403719761836f;
    const float LI127 = LOG1E4 / 127.f;
    const float LI255 = LOG1E4 / 255.f;

    for (int d = threadIdx.x; d < DM; d += 256) {
        float ip;
        if (d < 128)       ip = sinf(prv * expf(-(float)d * LI127));
        else if (d < 256)  ip = cosf(prv * expf(-(float)(d - 128) * LI127));
        else if (d < 384)  ip = sinf(pcv * expf(-(float)(d - 256) * LI127));
        else               ip = cosf(pcv * expf(-(float)(d - 384) * LI127));
        float tp;
        if (d < 256) tp = sinf(ptv * expf(-(float)d * LI255));
        else         tp = cosf(ptv * expf(-(float)(d - 256) * LI255));
        const float v = miv * (gI[(size_t)row * DM + d] + ip)
                      + mtv * (emb[(size_t)tok * DM + d] + tp);
        X[(size_t)row * DM + d] = v;
        Xh[(size_t)row * DM + d] = __float2bfloat16(v);
    }
}

// ---------------------------------------------------------------------------
// Fused partial-sum + bias + residual + LayerNorm (out may alias res).
// ---------------------------------------------------------------------------
__global__ __launch_bounds__(256) void ln_red(
    const float* __restrict__ P, int nP,
    const float* __restrict__ bias, const float* __restrict__ res,
    const float* __restrict__ g, const float* __restrict__ b,
    float* __restrict__ out, bf16* __restrict__ outh)
{
    const int row = blockIdx.x;
    const int tid = threadIdx.x;
    const size_t base = (size_t)row * DM;
    float x0 = res[base + tid] + bias[tid];
    float x1 = res[base + tid + 256] + bias[tid + 256];
    for (int p = 0; p < nP; ++p) {
        x0 += P[(size_t)p * 1048576 + base + tid];
        x1 += P[(size_t)p * 1048576 + base + tid + 256];
    }
    __shared__ float red[256];
    red[tid] = x0 + x1;
    __syncthreads();
    for (int off = 128; off > 0; off >>= 1) {
        if (tid < off) red[tid] += red[tid + off];
        __syncthreads();
    }
    const float mean = red[0] / (float)DM;
    __syncthreads();
    const float d0 = x0 - mean, d1 = x1 - mean;
    red[tid] = d0 * d0 + d1 * d1;
    __syncthreads();
    for (int off = 128; off > 0; off >>= 1) {
        if (tid < off) red[tid] += red[tid + off];
        __syncthreads();
    }
    const float var = red[0] / (float)DM;
    const float rstd = rsqrtf(var + 1e-5f);
    const float y0 = d0 * rstd * g[tid] + b[tid];
    const float y1 = d1 * rstd * g[tid + 256] + b[tid + 256];
    out[base + tid]        = y0;
    out[base + tid + 256]  = y1;
    outh[base + tid]       = __float2bfloat16(y0);
    outh[base + tid + 256] = __float2bfloat16(y1);
}

// ---------------------------------------------------------------------------
// Chunked-parallel linear attention.
// Kernel 1: raw chunk sums S_c = K_c^T @ V_c and ksum_c. Grid (16,8,2).
// ---------------------------------------------------------------------------
__global__ __launch_bounds__(256) void attn_kv(
    const float* __restrict__ Kp, const float* __restrict__ Vp,
    float* __restrict__ S, float* __restrict__ ks)
{
    const int c = blockIdx.x, h = blockIdx.y, n = blockIdx.z;
    const int tid = threadIdx.x;
    __shared__ float sK[64][64], sV[64][64], part[4][64];

    const int lr = tid >> 4;
    const int c4 = (tid & 15) * 4;
    #pragma unroll
    for (int it = 0; it < 4; ++it) {
        const int row = it * 16 + lr;
        const size_t gb = ((size_t)(n * LSEQ + c * 64 + row)) * QS + h * DKH + c4;
        *(float4*)&sK[row][c4] = *(const float4*)(Kp + gb);
        *(float4*)&sV[row][c4] = *(const float4*)(Vp + gb);
    }
    __syncthreads();

    const int e = tid & 63, dq = tid >> 6;
    float s[16] = {};
    for (int l = 0; l < 64; ++l) {
        const float vv = sV[l][e];
        const float4 k0 = *(const float4*)&sK[l][dq * 16 + 0];
        const float4 k1 = *(const float4*)&sK[l][dq * 16 + 4];
        const float4 k2 = *(const float4*)&sK[l][dq * 16 + 8];
        const float4 k3 = *(const float4*)&sK[l][dq * 16 + 12];
        s[0]  = fmaf(k0.x, vv, s[0]);  s[1]  = fmaf(k0.y, vv, s[1]);
        s[2]  = fmaf(k0.z, vv, s[2]);  s[3]  = fmaf(k0.w, vv, s[3]);
        s[4]  = fmaf(k1.x, vv, s[4]);  s[5]  = fmaf(k1.y, vv, s[5]);
        s[6]  = fmaf(k1.z, vv, s[6]);  s[7]  = fmaf(k1.w, vv, s[7]);
        s[8]  = fmaf(k2.x, vv, s[8]);  s[9]  = fmaf(k2.y, vv, s[9]);
        s[10] = fmaf(k2.z, vv, s[10]); s[11] = fmaf(k2.w, vv, s[11]);
        s[12] = fmaf(k3.x, vv, s[12]); s[13] = fmaf(k3.y, vv, s[13]);
        s[14] = fmaf(k3.z, vv, s[14]); s[15] = fmaf(k3.w, vv, s[15]);
    }
    const size_t sb = (((size_t)(n * NHEAD + h)) * NCHUNK + c) * 4096;
    #pragma unroll
    for (int i = 0; i < 16; ++i) S[sb + (size_t)(dq * 16 + i) * 64 + e] = s[i];

    float kp = 0.f;
    #pragma unroll
    for (int i = 0; i < 16; ++i) kp += sK[dq * 16 + i][e];
    part[dq][e] = kp;
    __syncthreads();
    if (tid < 64)
        ks[(((size_t)(n * NHEAD + h)) * NCHUNK + c) * 64 + tid] =
            part[0][tid] + part[1][tid] + part[2][tid] + part[3][tid];
}

// Kernel 2: O = Q@S_pre + tril(Q@K^T)@V. Prefix S_pre is summed inline from
// the raw chunk states of chunks < c (exclusive). Grid (16,8,2).
__global__ __launch_bounds__(256) void attn_out(
    const float* __restrict__ QKV, const float* __restrict__ S,
    const float* __restrict__ ks, bf16* __restrict__ O)
{
    const int c = blockIdx.x, h = blockIdx.y, n = blockIdx.z;
    const int tid = threadIdx.x;
    __shared__ float sQt[64][64];
    __shared__ float sKt[64][64];
    __shared__ float sV [64][64];
    __shared__ float sS [64][64];
    __shared__ float sPt[64][65];
    __shared__ float skp[64];

    const size_t nhS = ((size_t)(n * NHEAD + h)) * NCHUNK * 4096;
    const size_t nhK = ((size_t)(n * NHEAD + h)) * NCHUNK * 64;

    // inline exclusive prefix of chunk states
    {
        float4 aS[4] = {};
        for (int cc = 0; cc < c; ++cc) {
            const float* Sc = S + nhS + (size_t)cc * 4096;
            #pragma unroll
            for (int i = 0; i < 4; ++i) {
                const float4 t = *(const float4*)(Sc + i * 1024 + tid * 4);
                aS[i].x += t.x; aS[i].y += t.y; aS[i].z += t.z; aS[i].w += t.w;
            }
        }
        float* sSf = &sS[0][0];
        #pragma unroll
        for (int i = 0; i < 4; ++i)
            *(float4*)(sSf + i * 1024 + tid * 4) = aS[i];
        if (tid < 64) {
            float kp = 0.f;
            for (int cc = 0; cc < c; ++cc) kp += ks[nhK + cc * 64 + tid];
            skp[tid] = kp;
        }
    }

    const int lr = tid >> 4;
    const int c4 = (tid & 15) * 4;
    #pragma unroll
    for (int it = 0; it < 4; ++it) {
        const int row = it * 16 + lr;
        const size_t gb = ((size_t)(n * LSEQ + c * 64 + row)) * QS + h * DKH + c4;
        const float4 q4 = *(const float4*)(QKV + gb);
        const float4 k4 = *(const float4*)(QKV + gb + 512);
        const float4 v4 = *(const float4*)(QKV + gb + 1024);
        sQt[c4 + 0][row] = q4.x; sQt[c4 + 1][row] = q4.y;
        sQt[c4 + 2][row] = q4.z; sQt[c4 + 3][row] = q4.w;
        sKt[c4 + 0][row] = k4.x; sKt[c4 + 1][row] = k4.y;
        sKt[c4 + 2][row] = k4.z; sKt[c4 + 3][row] = k4.w;
        *(float4*)&sV[row][c4] = v4;
    }
    __syncthreads();

    const int m4 = (tid & 15) * 4;
    const int lg = tid >> 4;
    {
        float p[4][4] = {};
        for (int d = 0; d < 64; ++d) {
            const float4 k4 = *(const float4*)&sKt[d][m4];
            const float4 q4 = *(const float4*)&sQt[d][lg * 4];
            p[0][0] = fmaf(q4.x, k4.x, p[0][0]); p[0][1] = fmaf(q4.x, k4.y, p[0][1]);
            p[0][2] = fmaf(q4.x, k4.z, p[0][2]); p[0][3] = fmaf(q4.x, k4.w, p[0][3]);
            p[1][0] = fmaf(q4.y, k4.x, p[1][0]); p[1][1] = fmaf(q4.y, k4.y, p[1][1]);
            p[1][2] = fmaf(q4.y, k4.z, p[1][2]); p[1][3] = fmaf(q4.y, k4.w, p[1][3]);
            p[2][0] = fmaf(q4.z, k4.x, p[2][0]); p[2][1] = fmaf(q4.z, k4.y, p[2][1]);
            p[2][2] = fmaf(q4.z, k4.z, p[2][2]); p[2][3] = fmaf(q4.z, k4.w, p[2][3]);
            p[3][0] = fmaf(q4.w, k4.x, p[3][0]); p[3][1] = fmaf(q4.w, k4.y, p[3][1]);
            p[3][2] = fmaf(q4.w, k4.z, p[3][2]); p[3][3] = fmaf(q4.w, k4.w, p[3][3]);
        }
        #pragma unroll
        for (int jj = 0; jj < 4; ++jj)
            #pragma unroll
            for (int j = 0; j < 4; ++j)
                sPt[m4 + jj][lg * 4 + j] = p[j][jj];
    }
    __syncthreads();

    float acc[4][4] = {};
    float z[4] = {};
    const int lmax = lg * 4 + 3;
    for (int m = 0; m <= lmax; ++m) {
        const float4 v4 = *(const float4*)&sV[m][m4];
        #pragma unroll
        for (int j = 0; j < 4; ++j) {
            const int l = lg * 4 + j;
            float p = sPt[m][l];
            p = (m <= l) ? p : 0.f;
            z[j] += p;
            acc[j][0] = fmaf(p, v4.x, acc[j][0]);
            acc[j][1] = fmaf(p, v4.y, acc[j][1]);
            acc[j][2] = fmaf(p, v4.z, acc[j][2]);
            acc[j][3] = fmaf(p, v4.w, acc[j][3]);
        }
    }
    for (int d = 0; d < 64; ++d) {
        const float4 s4 = *(const float4*)&sS[d][m4];
        const float4 q4 = *(const float4*)&sQt[d][lg * 4];
        const float kp = skp[d];
        z[0] = fmaf(q4.x, kp, z[0]); z[1] = fmaf(q4.y, kp, z[1]);
        z[2] = fmaf(q4.z, kp, z[2]); z[3] = fmaf(q4.w, kp, z[3]);
        acc[0][0] = fmaf(q4.x, s4.x, acc[0][0]); acc[0][1] = fmaf(q4.x, s4.y, acc[0][1]);
        acc[0][2] = fmaf(q4.x, s4.z, acc[0][2]); acc[0][3] = fmaf(q4.x, s4.w, acc[0][3]);
        acc[1][0] = fmaf(q4.y, s4.x, acc[1][0]); acc[1][1] = fmaf(q4.y, s4.y, acc[1][1]);
        acc[1][2] = fmaf(q4.y, s4.z, acc[1][2]); acc[1][3] = fmaf(q4.y, s4.w, acc[1][3]);
        acc[2][0] = fmaf(q4.z, s4.x, acc[2][0]); acc[2][1] = fmaf(q4.z, s4.y, acc[2][1]);
        acc[2][2] = fmaf(q4.z, s4.z, acc[2][2]); acc[2][3] = fmaf(q4.z, s4.w, acc[2][3]);
        acc[3][0] = fmaf(q4.w, s4.x, acc[3][0]); acc[3][1] = fmaf(q4.w, s4.y, acc[3][1]);
        acc[3][2] = fmaf(q4.w, s4.z, acc[3][2]); acc[3][3] = fmaf(q4.w, s4.w, acc[3][3]);
    }
    #pragma unroll
    for (int j = 0; j < 4; ++j) {
        const int l = lg * 4 + j;
        const float rz = 1.f / (z[j] + 1e-6f);
        const size_t ob = ((size_t)(n * LSEQ + c * 64 + l)) * DM + h * DKH + m4;
        O[ob + 0] = __float2bfloat16(acc[j][0] * rz);
        O[ob + 1] = __float2bfloat16(acc[j][1] * rz);
        O[ob + 2] = __float2bfloat16(acc[j][2] * rz);
        O[ob + 3] = __float2bfloat16(acc[j][3] * rz);
    }
}

// ---------------------------------------------------------------------------
extern "C" void kernel_launch(void* const* d_in, const int* in_sizes, int n_in,
                              void* d_out, int out_size, void* d_ws, size_t ws_size,
                              hipStream_t stream)
{
    const float* x_img   = (const float*)d_in[0];
    const int*   x_txt   = (const int*)  d_in[1];
    const float* mask_i  = (const float*)d_in[2];
    const float* mask_t  = (const float*)d_in[3];
    const float* pos_r   = (const float*)d_in[4];
    const float* pos_c   = (const float*)d_in[5];
    const float* pos_t   = (const float*)d_in[6];
    const float* W_ei    = (const float*)d_in[7];
    const float* b_ei    = (const float*)d_in[8];
    const float* emb_txt = (const float*)d_in[9];
    const float* Wq      = (const float*)d_in[10];
    const float* bq      = (const float*)d_in[11];
    const float* Wk      = (const float*)d_in[12];
    const float* bk      = (const float*)d_in[13];
    const float* Wv      = (const float*)d_in[14];
    const float* bv      = (const float*)d_in[15];
    const float* Wo      = (const float*)d_in[16];
    const float* bo      = (const float*)d_in[17];
    const float* W1      = (const float*)d_in[18];
    const float* b1      = (const float*)d_in[19];
    const float* W2      = (const float*)d_in[20];
    const float* b2      = (const float*)d_in[21];
    const float* ln1_s   = (const float*)d_in[22];
    const float* ln1_b   = (const float*)d_in[23];
    const float* ln2_s   = (const float*)d_in[24];
    const float* ln2_b   = (const float*)d_in[25];
    const float* W_pi    = (const float*)d_in[26];
    const float* b_pi    = (const float*)d_in[27];
    const float* W_pt    = (const float*)d_in[28];
    const float* b_pt    = (const float*)d_in[29];

    float* ws = (float*)d_ws;
    size_t off = 0;
    auto alloc = [&](size_t nfloats) { float* p = ws + off; off += nfloats; return p; };

    float* Xb   = alloc(1048576);           // activations fp32 (N,L,D)
    float* Pb   = alloc(4194304);           // split-K partials / embed scratch
    float* QKVb = alloc(3145728);           // fused QKV fp32 (N,L,1536)
    float* Sb   = alloc(1048576);           // raw chunk KV sums
    float* ksb  = alloc(16384);
    float* qkvB = alloc(4 * QS);            // fused QKV bias
    float* hb   = alloc(8704);              // concat head bias
    bf16* Xh    = (bf16*)alloc(524288);     // activations bf16
    bf16* Ob    = (bf16*)alloc(524288);     // attention out bf16
    bf16* Tb    = (bf16*)alloc(2097152);    // FF intermediate bf16 (N,L,FF)
    bf16* ximgh = (bf16*)alloc(524288);
    bf16* QKVt  = (bf16*)alloc(1572864);    // (NL,1536,512)
    bf16* Wot   = (bf16*)alloc(524288);     // (NL,512,512)
    bf16* W1t   = (bf16*)alloc(2097152);    // (NL,2048,512)
    bf16* W2t   = (bf16*)alloc(2097152);    // (NL,512,2048)
    bf16* Weit  = (bf16*)alloc(131072);     // (512,512)
    bf16* Whead = (bf16*)alloc(2195456);    // (8576,512)

    const dim3 blk(256);
    const dim3 gAttn(NCHUNK, NHEAD, NB);

    // ---- one setup dispatch: all casts + biases ----
    setup_all<<<dim3(CO_END), blk, 0, stream>>>(
        Wq, Wk, Wv, Wo, W1, W2, W_ei, W_pi, W_pt,
        QKVt, Wot, W1t, W2t, Weit, Whead,
        x_img, ximgh, bq, bk, bv, qkvB, b_pi, b_pt, hb);

    // ---- embedding ----
    gemm16<64, 64><<<dim3(8, 32), blk, 0, stream>>>(
        ximgh, Weit, b_ei, nullptr, Pb, nullptr, nullptr, NROWS, 512, 512, OP_NONE, 512);
    embed_k<<<NROWS, blk, 0, stream>>>(Pb, x_txt, emb_txt, mask_i, mask_t,
                                       pos_r, pos_c, pos_t, Xb, Xh);

    for (int i = 0; i < NLAYER; ++i) {
        // fused QKV projection (elu+1 on Q,K cols)
        gemm16<64, 128><<<dim3(12, 32), blk, 0, stream>>>(
            Xh, QKVt + (size_t)i * 786432, qkvB + i * QS, nullptr,
            QKVb, nullptr, nullptr, NROWS, 512, QS, OP_QKV, 512);

        attn_kv<<<gAttn, blk, 0, stream>>>(QKVb + 512, QKVb + 1024, Sb, ksb);
        attn_out<<<gAttn, blk, 0, stream>>>(QKVb, Sb, ksb, Ob);

        // out proj (split-K=2 partials) -> fused reduce+residual+LN1
        gemm16<64, 64><<<dim3(8, 32, 2), blk, 0, stream>>>(
            Ob, Wot + (size_t)i * 262144, nullptr, nullptr,
            Pb, nullptr, nullptr, NROWS, 512, 512, OP_PART, 256);
        ln_red<<<NROWS, blk, 0, stream>>>(Pb, 2, bo + (size_t)i * DM, Xb,
                                          ln1_s + (size_t)i * DM,
                                          ln1_b + (size_t)i * DM, Xb, Xh);

        // FF1 (gelu fused) -> FF2 (split-K=4) -> fused reduce+residual+LN2
        gemm16<64, 128><<<dim3(16, 32), blk, 0, stream>>>(
            Xh, W1t + (size_t)i * 1048576, b1 + (size_t)i * FFD, nullptr,
            nullptr, nullptr, Tb, NROWS, 512, FFD, OP_GELU, 512);
        gemm16<64, 64><<<dim3(8, 32, 4), blk, 0, stream>>>(
            Tb, W2t + (size_t)i * 1048576, nullptr, nullptr,
            Pb, nullptr, nullptr, NROWS, 2048, 512, OP_PART, 512);
        ln_red<<<NROWS, blk, 0, stream>>>(Pb, 4, b2 + (size_t)i * DM, Xb,
                                          ln2_s + (size_t)i * DM,
                                          ln2_b + (size_t)i * DM, Xb, Xh);
    }

    // ---- merged heads, M-fastest grid for B-tile L2 reuse ----
    float* out = (float*)d_out;
    gemm16<128, 128><<<dim3(16, 67), blk, 0, stream>>>(
        Xh, Whead, hb, nullptr, out, out + 1048576, nullptr,
        NROWS, 512, NHEADCAT, OP_HEAD, 512);
}